// Round 18
// baseline (126.983 us; speedup 1.0000x reference)
//
#include <hip/hip_runtime.h>
#include <hip/hip_bf16.h>
#include <hip/hip_fp16.h>
#include <math.h>

#define NB 16
#define NS 1024
#define NM 256
#define NH 8
#define NDK 32
#define NL 2

typedef __attribute__((ext_vector_type(4))) float f32x4;
typedef __attribute__((ext_vector_type(4))) short bf16x4u;
typedef __attribute__((ext_vector_type(8))) _Float16 f16x8;
typedef __attribute__((ext_vector_type(2))) _Float16 f16x2;

#if __has_builtin(__builtin_amdgcn_exp2f)
#define EXP2F(x) __builtin_amdgcn_exp2f(x)
#else
#define EXP2F(x) exp2f(x)
#endif

__device__ __forceinline__ unsigned short f2h(float f) {
  _Float16 h = (_Float16)f;
  return __builtin_bit_cast(unsigned short, h);
}
__device__ __forceinline__ float h2f(unsigned short u) {
  return (float)__builtin_bit_cast(_Float16, u);
}

// packed f16 weight word: w2 = max(e1p*e2p, e1n*e2n) & mask (2 elems/op)
__device__ __forceinline__ unsigned int wword(unsigned int pw, unsigned int nw,
                                              f16x2 e1p2, f16x2 e1n2,
                                              unsigned int mk) {
  f16x2 hp = __builtin_bit_cast(f16x2, pw);
  f16x2 hn = __builtin_bit_cast(f16x2, nw);
  f16x2 w = __builtin_elementwise_max(hp * e1p2, hn * e1n2);
  return __builtin_bit_cast(unsigned int, w) & mk;
}

// ---------------------------------------------------------------------------
// Mask-pack: one int32 0/1 array -> bitmask. inv!=0 packs (v==0).
// Single stream, 16B/lane int4 loads, 8-deep load hoisting.
// If orc != nullptr, also ORs the packed word into orc (combined mask).
__global__ __launch_bounds__(256) void pack_kernel(
    const int* __restrict__ src, unsigned int* __restrict__ dst, int inv,
    unsigned int* __restrict__ orc)
{
  int wid = blockIdx.x * 4 + (threadIdx.x >> 6);
  int lane = threadIdx.x & 63;
  size_t eb = (size_t)wid * 2048;
  const int4* a4 = (const int4*)(src + eb);
  int lg = lane >> 3;
  int sh = (lane & 7) * 4;
  unsigned int xo = inv ? 15u : 0u;
  int4 v[8];
#pragma unroll
  for (int k = 0; k < 8; ++k) v[k] = a4[k * 64 + lane];
#pragma unroll
  for (int k = 0; k < 8; ++k) {
    unsigned int nc = ((v[k].x != 0) ? 1u : 0u) | ((v[k].y != 0) ? 2u : 0u) |
                      ((v[k].z != 0) ? 4u : 0u) | ((v[k].w != 0) ? 8u : 0u);
    nc ^= xo;
    unsigned int vc = nc << sh;
    vc |= __shfl_xor(vc, 1, 64);
    vc |= __shfl_xor(vc, 2, 64);
    vc |= __shfl_xor(vc, 4, 64);
    if ((lane & 7) == 0) {
      size_t wi = (size_t)wid * 64 + k * 8 + lg;
      dst[wi] = vc;
      if (orc) orc[wi] |= vc;
    }
  }
}

// ---------------------------------------------------------------------------
// Transpose proj_w (L,H,M,DK) f32 -> Wt (L,H,DK,M) f16. Block = one (l,h).
__global__ __launch_bounds__(256) void wprep_kernel(
    const float* __restrict__ pw, unsigned short* __restrict__ Wt)
{
  __shared__ float lw[256][36];
  int lh = blockIdx.x;                 // 0..15
  int t = threadIdx.x;
  const float* src = pw + (size_t)lh * NM * NDK;
#pragma unroll
  for (int q = 0; q < 8; ++q) {
    int e0 = q * 1024 + t * 4;
    int m = e0 >> 5, dc = e0 & 31;
    f32x4 v = *(const f32x4*)(src + e0);
    *(f32x4*)&lw[m][dc] = v;
  }
  __syncthreads();
  unsigned short* out = Wt + (size_t)lh * NDK * NM;
#pragma unroll
  for (int q = 0; q < 4; ++q) {
    int idx = q * 2048 + t * 8;
    int d = idx >> 8, m = idx & 255;
    unsigned short ov[8];
#pragma unroll
    for (int j = 0; j < 8; ++j) ov[j] = f2h(lw[m + j][d]);
    *(uint4*)(out + (size_t)d * NM + m) = *(uint4*)ov;
  }
}

// ---------------------------------------------------------------------------
// Projection GEMM -> Pt[b][h][d][s] (f16) + fused s1/s2 epilogue.
__global__ __launch_bounds__(256) void proj_kernel(
    const float* __restrict__ x, const unsigned short* __restrict__ Wt,
    const float* __restrict__ pb, const float* __restrict__ aw,
    const float* __restrict__ abp,
    unsigned short* __restrict__ Pt, float* __restrict__ s1o,
    unsigned short* __restrict__ s2po, unsigned short* __restrict__ s2no)
{
  __shared__ unsigned short As[64][40];
  __shared__ unsigned short Bs[64][40];

  const float LOG2E = 1.4426950408889634f;
  int ct = blockIdx.x, rt = blockIdx.y, t = threadIdx.x;
  int w = t >> 6, lane = t & 63;
  int il = lane & 15, g4 = lane >> 4;
  int wi = w >> 1, wc = w & 1;

  f32x4 acc[2][2] = {};
  int arow = t >> 2, akoff = (t & 3) * 8;

  for (int k0 = 0; k0 < NM; k0 += 32) {
    const float* xp = x + (size_t)(rt * 64 + arow) * NM + k0 + akoff;
    f32x4 v0 = *(const f32x4*)xp;
    f32x4 v1 = *(const f32x4*)(xp + 4);
    unsigned short av[8];
    av[0] = f2h(v0[0]); av[1] = f2h(v0[1]); av[2] = f2h(v0[2]); av[3] = f2h(v0[3]);
    av[4] = f2h(v1[0]); av[5] = f2h(v1[1]); av[6] = f2h(v1[2]); av[7] = f2h(v1[3]);
    *(uint4*)&As[arow][akoff] = *(uint4*)av;
    uint4 bv = *(const uint4*)(Wt + (size_t)(ct * 64 + arow) * NM + k0 + akoff);
    *(uint4*)&Bs[arow][akoff] = bv;
    __syncthreads();

    f16x8 af0 = *(f16x8*)&As[wi * 32 + il][g4 * 8];
    f16x8 af1 = *(f16x8*)&As[wi * 32 + 16 + il][g4 * 8];
    f16x8 bf0 = *(f16x8*)&Bs[wc * 32 + il][g4 * 8];
    f16x8 bf1 = *(f16x8*)&Bs[wc * 32 + 16 + il][g4 * 8];
    acc[0][0] = __builtin_amdgcn_mfma_f32_16x16x32_f16(af0, bf0, acc[0][0], 0, 0, 0);
    acc[0][1] = __builtin_amdgcn_mfma_f32_16x16x32_f16(af0, bf1, acc[0][1], 0, 0, 0);
    acc[1][0] = __builtin_amdgcn_mfma_f32_16x16x32_f16(af1, bf0, acc[1][0], 0, 0, 0);
    acc[1][1] = __builtin_amdgcn_mfma_f32_16x16x32_f16(af1, bf1, acc[1][1], 0, 0, 0);
    __syncthreads();
  }

  int head = ct * 2 + wc;
  float a1v[2] = {aw[il], aw[16 + il]};
  float a2v[2] = {aw[32 + il], aw[48 + il]};
  float ab = abp[0];

#pragma unroll
  for (int ih = 0; ih < 2; ++ih) {
    float s1p[4] = {0.f, 0.f, 0.f, 0.f};
    float s2p[4] = {0.f, 0.f, 0.f, 0.f};
    int r0 = rt * 64 + wi * 32 + ih * 16 + g4 * 4;
    int bb = r0 >> 10, ss = r0 & 1023;
#pragma unroll
    for (int dh = 0; dh < 2; ++dh) {
      int colhd = ct * 64 + wc * 32 + dh * 16 + il;
      int dd = colhd & 31;
      float bias = pb[colhd];
      f32x4 c = acc[ih][dh];
      unsigned short ov[4];
#pragma unroll
      for (int e = 0; e < 4; ++e) {
        float Pv = c[e] + bias;
        ov[e] = f2h(Pv);
        s1p[e] += Pv * a1v[dh];
        s2p[e] += Pv * a2v[dh];
      }
      size_t idx = ((size_t)(bb * NH + head) * NDK + dd) * NS + ss;
      *(bf16x4u*)(Pt + idx) = *(bf16x4u*)ov;
    }
#pragma unroll
    for (int e = 0; e < 4; ++e) {
#pragma unroll
      for (int off = 1; off <= 8; off <<= 1) {
        s1p[e] += __shfl_xor(s1p[e], off, 64);
        s2p[e] += __shfl_xor(s2p[e], off, 64);
      }
    }
    if (il == 0) {
      size_t sb = (size_t)(bb * NH + head) * NS + ss;
#pragma unroll
      for (int e = 0; e < 4; ++e) {
        s1o[sb + e] = s1p[e] * LOG2E;
        float s2L = (s2p[e] + ab) * LOG2E;
        s2L = fminf(fmaxf(s2L, -7.5f), 7.5f);
        s2po[sb + e] = f2h(EXP2F(s2L));
        s2no[sb + e] = f2h(EXP2F(0.2f * s2L));
      }
    }
  }
}

// ---------------------------------------------------------------------------
// Attention, LDS-staged f16 Pt, packed-f16 weight math. SINGLE mask array
// (pkc = combined, precomputed at pack time; pks for type==1 layers>0).
__global__ __launch_bounds__(512) void attn_kernel(
    const unsigned short* __restrict__ Pt,    // (B,H,DK,S) f16
    const float* __restrict__ s1a,            // (B,H,S), log2e-scaled
    const unsigned short* __restrict__ s2pa,  // f16 exp2(s2L)
    const unsigned short* __restrict__ s2na,  // f16 exp2(0.2*s2L)
    const unsigned int* __restrict__ pkc,     // combined mask bits
    const unsigned int* __restrict__ pks,     // smask-only bits
    const int* __restrict__ typep,
    int layer,
    unsigned short* __restrict__ co)          // (B,S,M) f16 concat out
{
  __shared__ __align__(16) unsigned short ptl[32 * 512];  // 32KB, swizzled
  __shared__ __align__(16) unsigned short e2pl[1024];     // 2KB f16
  __shared__ __align__(16) unsigned short e2nl[1024];     // 2KB f16
  __shared__ uint4 mtab[256];                             // 4KB

  int orig = blockIdx.x;
  int lb = (orig & 7) * 64 + (orig >> 3);
  int iq = lb & 3, bh = lb >> 2;
  int b = bh >> 3, h = bh & 7;

  int t = threadIdx.x, w = t >> 6, lane = t & 63;
  int il = lane & 15, g4 = lane >> 4;
  int xorv = (il & 7) << 4;

  if (t < 256) {
    unsigned int m = t;
    uint4 e;
    e.x = ((m & 1u)   ? 0u : 0xFFFFu) | ((m & 2u)   ? 0u : 0xFFFF0000u);
    e.y = ((m & 4u)   ? 0u : 0xFFFFu) | ((m & 8u)   ? 0u : 0xFFFF0000u);
    e.z = ((m & 16u)  ? 0u : 0xFFFFu) | ((m & 32u)  ? 0u : 0xFFFF0000u);
    e.w = ((m & 64u)  ? 0u : 0xFFFFu) | ((m & 128u) ? 0u : 0xFFFF0000u);
    mtab[t] = e;
  }

  const unsigned char* pm = (const unsigned char*)(
      (typep[0] == 1 && layer > 0) ? pks : pkc);
  const unsigned short* ptg = Pt + (size_t)bh * NDK * NS;

  f16x8 ones;
#pragma unroll
  for (int e = 0; e < 8; ++e) ones[e] = (_Float16)1.0f;

  int rbase = iq * 256 + w * 32;
  f16x2 e1p2[2], e1n2[2];
  size_t mbyte[2];
#pragma unroll
  for (int g = 0; g < 2; ++g) {
    float s1L = s1a[(size_t)bh * NS + rbase + g * 16 + il];
    s1L = fminf(fmaxf(s1L, -7.5f), 7.5f);
    _Float16 hp = (_Float16)EXP2F(s1L);
    _Float16 hn = (_Float16)EXP2F(0.2f * s1L);
    e1p2[g][0] = hp; e1p2[g][1] = hp;
    e1n2[g][0] = hn; e1n2[g][1] = hn;
    mbyte[g] = ((size_t)(b * NS + rbase + g * 16 + il) * NS) >> 3;
  }

  f32x4 acc[2][2] = {};
  f32x4 accd[2] = {};

  for (int jh = 0; jh < 2; ++jh) {
    __syncthreads();
    {
      const char* srcb = (const char*)ptg;
#pragma unroll
      for (int q = 0; q < 4; ++q) {
        int pos = q * 8192 + t * 16;
        int r = pos >> 10;
        int incol = pos & 1023;
        uint4 v = *(const uint4*)(srcb + r * 2048 + jh * 1024 + incol);
        *(uint4*)((char*)ptl + r * 1024 + (incol ^ ((r & 7) << 4))) = v;
      }
      if (jh == 0) {
        if (t < 128)
          ((uint4*)e2pl)[t] = *(const uint4*)(s2pa + (size_t)bh * NS + t * 8);
        else if (t < 256)
          ((uint4*)e2nl)[t - 128] =
              *(const uint4*)(s2na + (size_t)bh * NS + (t - 128) * 8);
      }
    }
    __syncthreads();

    for (int jg = 0; jg < 512; jg += 128) {
      size_t off = (size_t)((jh * 512 + jg) >> 3);
      uint4 mk0 = *(const uint4*)(pm + mbyte[0] + off);
      uint4 mk1 = *(const uint4*)(pm + mbyte[1] + off);
#pragma unroll
      for (int s = 0; s < 4; ++s) {
        unsigned int mb0 = ((&mk0.x)[s] >> (g4 * 8)) & 0xFFu;
        unsigned int mb1 = ((&mk1.x)[s] >> (g4 * 8)) & 0xFFu;
        uint4 am0 = mtab[mb0];
        uint4 am1 = mtab[mb1];
        int jl = jg + s * 32 + g4 * 8;
        int coff = (jl * 2) ^ xorv;
        const char* prow = (const char*)ptl + il * 1024;
        f16x8 b0 = *(const f16x8*)(prow + coff);
        f16x8 b1 = *(const f16x8*)(prow + 16 * 1024 + coff);
        int jfull = jh * 512 + jl;
        uint4 p4 = *(const uint4*)&e2pl[jfull];
        uint4 n4 = *(const uint4*)&e2nl[jfull];
        uint4 w0, w1;
        w0.x = wword(p4.x, n4.x, e1p2[0], e1n2[0], am0.x);
        w0.y = wword(p4.y, n4.y, e1p2[0], e1n2[0], am0.y);
        w0.z = wword(p4.z, n4.z, e1p2[0], e1n2[0], am0.z);
        w0.w = wword(p4.w, n4.w, e1p2[0], e1n2[0], am0.w);
        w1.x = wword(p4.x, n4.x, e1p2[1], e1n2[1], am1.x);
        w1.y = wword(p4.y, n4.y, e1p2[1], e1n2[1], am1.y);
        w1.z = wword(p4.z, n4.z, e1p2[1], e1n2[1], am1.z);
        w1.w = wword(p4.w, n4.w, e1p2[1], e1n2[1], am1.w);
        f16x8 af0 = __builtin_bit_cast(f16x8, w0);
        f16x8 af1 = __builtin_bit_cast(f16x8, w1);
        acc[0][0] = __builtin_amdgcn_mfma_f32_16x16x32_f16(af0, b0, acc[0][0], 0, 0, 0);
        acc[0][1] = __builtin_amdgcn_mfma_f32_16x16x32_f16(af0, b1, acc[0][1], 0, 0, 0);
        accd[0]   = __builtin_amdgcn_mfma_f32_16x16x32_f16(af0, ones, accd[0], 0, 0, 0);
        acc[1][0] = __builtin_amdgcn_mfma_f32_16x16x32_f16(af1, b0, acc[1][0], 0, 0, 0);
        acc[1][1] = __builtin_amdgcn_mfma_f32_16x16x32_f16(af1, b1, acc[1][1], 0, 0, 0);
        accd[1]   = __builtin_amdgcn_mfma_f32_16x16x32_f16(af1, ones, accd[1], 0, 0, 0);
      }
    }
  }

#pragma unroll
  for (int g = 0; g < 2; ++g) {
    f32x4 rd;
#pragma unroll
    for (int e = 0; e < 4; ++e) rd[e] = __builtin_amdgcn_rcpf(accd[g][e]);
    unsigned short* cob =
        co + (size_t)(b * NS + rbase + g * 16 + g4 * 4) * NM + h * 32 + il;
#pragma unroll
    for (int e = 0; e < 4; ++e) {
      cob[(size_t)e * NM] = f2h(acc[g][0][e] * rd[e]);
      cob[(size_t)e * NM + 16] = f2h(acc[g][1][e] * rd[e]);
    }
  }
}

// ---------------------------------------------------------------------------
// Residual + LayerNorm: row r -> LN(xin[r] + co[r]) * g + b.  co is f16.
__global__ __launch_bounds__(256) void ln_kernel(
    const float* __restrict__ xin, const unsigned short* __restrict__ co,
    const float* __restrict__ lng, const float* __restrict__ lnb,
    float* __restrict__ xout)
{
  int row = blockIdx.x * 4 + (threadIdx.x >> 6);
  int lane = threadIdx.x & 63;
  size_t base = (size_t)row * NM + lane * 4;
  ushort4 cv = *(const ushort4*)(co + base);
  f32x4 xv = *(const f32x4*)(xin + base);
  f32x4 r;
  r[0] = xv[0] + h2f(cv.x);
  r[1] = xv[1] + h2f(cv.y);
  r[2] = xv[2] + h2f(cv.z);
  r[3] = xv[3] + h2f(cv.w);
  float sm = r[0] + r[1] + r[2] + r[3];
  float sq = r[0] * r[0] + r[1] * r[1] + r[2] * r[2] + r[3] * r[3];
#pragma unroll
  for (int off = 32; off >= 1; off >>= 1) {
    sm += __shfl_xor(sm, off, 64);
    sq += __shfl_xor(sq, off, 64);
  }
  float mu = sm * (1.f / 256.f);
  float var = sq * (1.f / 256.f) - mu * mu;
  float inv = rsqrtf(var + 1e-5f);
  f32x4 gv = *(const f32x4*)(lng + lane * 4);
  f32x4 bv = *(const f32x4*)(lnb + lane * 4);
  f32x4 o;
#pragma unroll
  for (int e = 0; e < 4; ++e) o[e] = (r[e] - mu) * inv * gv[e] + bv[e];
  *(f32x4*)(xout + base) = o;
}

// ---------------------------------------------------------------------------
extern "C" void kernel_launch(void* const* d_in, const int* in_sizes, int n_in,
                              void* d_out, int out_size, void* d_ws, size_t ws_size,
                              hipStream_t stream)
{
  const int* adj = (const int*)d_in[0];
  const float* inputs = (const float*)d_in[1];
  const int* smask = (const int*)d_in[2];
  const int* typep = (const int*)d_in[3];
  const float* proj_w = (const float*)d_in[4];
  const float* proj_b = (const float*)d_in[5];
  const float* attn_w = (const float*)d_in[6];
  const float* attn_b = (const float*)d_in[7];
  const float* ln_g = (const float*)d_in[8];
  const float* ln_b = (const float*)d_in[9];
  float* out = (float*)d_out;

  char* ws = (char*)d_ws;
  unsigned int* pkc = (unsigned int*)(ws);                      // 2 MB (combined)
  unsigned int* pks = (unsigned int*)(ws + (2u << 20));         // 2 MB (smask)
  unsigned short* Pt = (unsigned short*)(ws + (4u << 20));      // 8 MB
  float* s1 = (float*)(ws + (12u << 20));                       // 512 KB
  unsigned short* s2p = (unsigned short*)(ws + (12u << 20) + (1u << 19)); // 256 KB
  unsigned short* s2n = (unsigned short*)(ws + (13u << 20));    // 256 KB
  float* x1 = (float*)(ws + (14u << 20));                       // 16 MB
  unsigned short* Wt = (unsigned short*)(ws + (30u << 20));     // 256 KB
  unsigned short* co = (unsigned short*)(ws + (31u << 20));     // 8 MB f16

  // Serial schedule; combined mask produced at pack time.
  wprep_kernel<<<16, 256, 0, stream>>>(proj_w, Wt);
  pack_kernel<<<2048, 256, 0, stream>>>(adj, pkc, 1, nullptr);
  pack_kernel<<<2048, 256, 0, stream>>>(smask, pks, 0, pkc);

  for (int l = 0; l < NL; ++l) {
    const float* xin = (l == 0) ? inputs : x1;
    float* xout = (l == NL - 1) ? out : x1;
    proj_kernel<<<dim3(4, 256), 256, 0, stream>>>(
        xin, Wt + (size_t)l * NH * NDK * NM, proj_b + (size_t)l * NH * NDK,
        attn_w + l * 64, attn_b + l, Pt, s1, s2p, s2n);
    attn_kernel<<<512, 512, 0, stream>>>(
        Pt, s1, s2p, s2n, pkc, pks, typep, l, co);
    ln_kernel<<<4096, 256, 0, stream>>>(
        xin, co, ln_g + l * NM, ln_b + l * NM, xout);
  }
}

// Round 19
// 120.201 us; speedup vs baseline: 1.0564x; 1.0564x over previous
//
#include <hip/hip_runtime.h>
#include <hip/hip_bf16.h>
#include <hip/hip_fp16.h>
#include <math.h>

#define NB 16
#define NS 1024
#define NM 256
#define NH 8
#define NDK 32
#define NL 2

typedef __attribute__((ext_vector_type(4))) float f32x4;
typedef __attribute__((ext_vector_type(4))) short bf16x4u;
typedef __attribute__((ext_vector_type(8))) _Float16 f16x8;
typedef __attribute__((ext_vector_type(2))) _Float16 f16x2;

#if __has_builtin(__builtin_amdgcn_exp2f)
#define EXP2F(x) __builtin_amdgcn_exp2f(x)
#else
#define EXP2F(x) exp2f(x)
#endif

__device__ __forceinline__ unsigned short f2h(float f) {
  _Float16 h = (_Float16)f;
  return __builtin_bit_cast(unsigned short, h);
}
__device__ __forceinline__ float h2f(unsigned short u) {
  return (float)__builtin_bit_cast(_Float16, u);
}

// packed f16 weight word: w2 = max(e1p*e2p, e1n*e2n) & mask (2 elems/op)
__device__ __forceinline__ unsigned int wword(unsigned int pw, unsigned int nw,
                                              f16x2 e1p2, f16x2 e1n2,
                                              unsigned int mk) {
  f16x2 hp = __builtin_bit_cast(f16x2, pw);
  f16x2 hn = __builtin_bit_cast(f16x2, nw);
  f16x2 w = __builtin_elementwise_max(hp * e1p2, hn * e1n2);
  return __builtin_bit_cast(unsigned int, w) & mk;
}

// ---------------------------------------------------------------------------
// Transpose proj_w (L,H,M,DK) f32 -> Wt (L,H,DK,M) f16. Block = one (l,h).
__global__ __launch_bounds__(256) void wprep_kernel(
    const float* __restrict__ pw, unsigned short* __restrict__ Wt)
{
  __shared__ float lw[256][36];
  int lh = blockIdx.x;                 // 0..15
  int t = threadIdx.x;
  const float* src = pw + (size_t)lh * NM * NDK;
#pragma unroll
  for (int q = 0; q < 8; ++q) {
    int e0 = q * 1024 + t * 4;
    int m = e0 >> 5, dc = e0 & 31;
    f32x4 v = *(const f32x4*)(src + e0);
    *(f32x4*)&lw[m][dc] = v;
  }
  __syncthreads();
  unsigned short* out = Wt + (size_t)lh * NDK * NM;
#pragma unroll
  for (int q = 0; q < 4; ++q) {
    int idx = q * 2048 + t * 8;
    int d = idx >> 8, m = idx & 255;
    unsigned short ov[8];
#pragma unroll
    for (int j = 0; j < 8; ++j) ov[j] = f2h(lw[m + j][d]);
    *(uint4*)(out + (size_t)d * NM + m) = *(uint4*)ov;
  }
}

// ---------------------------------------------------------------------------
// Projection GEMM body -> Pt[b][h][d][s] (f16) + fused s1/s2 epilogue.
__device__ __forceinline__ void proj_body(
    int ct, int rt, int t,
    const float* __restrict__ x, const unsigned short* __restrict__ Wt,
    const float* __restrict__ pb, const float* __restrict__ aw,
    const float* __restrict__ abp,
    unsigned short* __restrict__ Pt, float* __restrict__ s1o,
    unsigned short* __restrict__ s2po, unsigned short* __restrict__ s2no,
    unsigned short (*As)[40], unsigned short (*Bs)[40])
{
  const float LOG2E = 1.4426950408889634f;
  int w = t >> 6, lane = t & 63;
  int il = lane & 15, g4 = lane >> 4;
  int wi = w >> 1, wc = w & 1;

  f32x4 acc[2][2] = {};
  int arow = t >> 2, akoff = (t & 3) * 8;

  for (int k0 = 0; k0 < NM; k0 += 32) {
    const float* xp = x + (size_t)(rt * 64 + arow) * NM + k0 + akoff;
    f32x4 v0 = *(const f32x4*)xp;
    f32x4 v1 = *(const f32x4*)(xp + 4);
    unsigned short av[8];
    av[0] = f2h(v0[0]); av[1] = f2h(v0[1]); av[2] = f2h(v0[2]); av[3] = f2h(v0[3]);
    av[4] = f2h(v1[0]); av[5] = f2h(v1[1]); av[6] = f2h(v1[2]); av[7] = f2h(v1[3]);
    *(uint4*)&As[arow][akoff] = *(uint4*)av;
    uint4 bv = *(const uint4*)(Wt + (size_t)(ct * 64 + arow) * NM + k0 + akoff);
    *(uint4*)&Bs[arow][akoff] = bv;
    __syncthreads();

    f16x8 af0 = *(f16x8*)&As[wi * 32 + il][g4 * 8];
    f16x8 af1 = *(f16x8*)&As[wi * 32 + 16 + il][g4 * 8];
    f16x8 bf0 = *(f16x8*)&Bs[wc * 32 + il][g4 * 8];
    f16x8 bf1 = *(f16x8*)&Bs[wc * 32 + 16 + il][g4 * 8];
    acc[0][0] = __builtin_amdgcn_mfma_f32_16x16x32_f16(af0, bf0, acc[0][0], 0, 0, 0);
    acc[0][1] = __builtin_amdgcn_mfma_f32_16x16x32_f16(af0, bf1, acc[0][1], 0, 0, 0);
    acc[1][0] = __builtin_amdgcn_mfma_f32_16x16x32_f16(af1, bf0, acc[1][0], 0, 0, 0);
    acc[1][1] = __builtin_amdgcn_mfma_f32_16x16x32_f16(af1, bf1, acc[1][1], 0, 0, 0);
    __syncthreads();
  }

  int head = ct * 2 + wc;
  float a1v[2] = {aw[il], aw[16 + il]};
  float a2v[2] = {aw[32 + il], aw[48 + il]};
  float ab = abp[0];

#pragma unroll
  for (int ih = 0; ih < 2; ++ih) {
    float s1p[4] = {0.f, 0.f, 0.f, 0.f};
    float s2p[4] = {0.f, 0.f, 0.f, 0.f};
    int r0 = rt * 64 + wi * 32 + ih * 16 + g4 * 4;
    int bb = r0 >> 10, ss = r0 & 1023;
#pragma unroll
    for (int dh = 0; dh < 2; ++dh) {
      int colhd = ct * 64 + wc * 32 + dh * 16 + il;
      int dd = colhd & 31;
      float bias = pb[colhd];
      f32x4 c = acc[ih][dh];
      unsigned short ov[4];
#pragma unroll
      for (int e = 0; e < 4; ++e) {
        float Pv = c[e] + bias;
        ov[e] = f2h(Pv);
        s1p[e] += Pv * a1v[dh];
        s2p[e] += Pv * a2v[dh];
      }
      size_t idx = ((size_t)(bb * NH + head) * NDK + dd) * NS + ss;
      *(bf16x4u*)(Pt + idx) = *(bf16x4u*)ov;
    }
#pragma unroll
    for (int e = 0; e < 4; ++e) {
#pragma unroll
      for (int off = 1; off <= 8; off <<= 1) {
        s1p[e] += __shfl_xor(s1p[e], off, 64);
        s2p[e] += __shfl_xor(s2p[e], off, 64);
      }
    }
    if (il == 0) {
      size_t sb = (size_t)(bb * NH + head) * NS + ss;
#pragma unroll
      for (int e = 0; e < 4; ++e) {
        s1o[sb + e] = s1p[e] * LOG2E;
        float s2L = (s2p[e] + ab) * LOG2E;
        s2L = fminf(fmaxf(s2L, -7.5f), 7.5f);
        s2po[sb + e] = f2h(EXP2F(s2L));
        s2no[sb + e] = f2h(EXP2F(0.2f * s2L));
      }
    }
  }
}

// ---------------------------------------------------------------------------
// Fused prelude: blocks [0,2048) pack adj==0 bits -> pka; [2048,4096) pack
// smask bits -> pks; [4096,5120) proj layer 0. All overlap on the device.
__global__ __launch_bounds__(256) void prelude_kernel(
    const int* __restrict__ adj, const int* __restrict__ smask,
    unsigned int* __restrict__ pka, unsigned int* __restrict__ pks,
    const float* __restrict__ x, const unsigned short* __restrict__ Wt0,
    const float* __restrict__ pb0, const float* __restrict__ aw0,
    const float* __restrict__ ab0,
    unsigned short* __restrict__ Pt, float* __restrict__ s1o,
    unsigned short* __restrict__ s2po, unsigned short* __restrict__ s2no)
{
  __shared__ unsigned short As[64][40];
  __shared__ unsigned short Bs[64][40];

  int bid = blockIdx.x;
  int t = threadIdx.x;
  if (bid < 4096) {
    const int* src = (bid < 2048) ? adj : smask;
    unsigned int* dst = (bid < 2048) ? pka : pks;
    unsigned int xo = (bid < 2048) ? 15u : 0u;
    int wid = (bid & 2047) * 4 + (t >> 6);
    int lane = t & 63;
    size_t eb = (size_t)wid * 2048;
    const int4* a4 = (const int4*)(src + eb);
    int lg = lane >> 3;
    int sh = (lane & 7) * 4;
#pragma unroll
    for (int k = 0; k < 8; ++k) {
      int4 v = a4[k * 64 + lane];
      unsigned int nc = ((v.x != 0) ? 1u : 0u) | ((v.y != 0) ? 2u : 0u) |
                        ((v.z != 0) ? 4u : 0u) | ((v.w != 0) ? 8u : 0u);
      nc ^= xo;
      unsigned int vc = nc << sh;
      vc |= __shfl_xor(vc, 1, 64);
      vc |= __shfl_xor(vc, 2, 64);
      vc |= __shfl_xor(vc, 4, 64);
      if ((lane & 7) == 0) dst[(size_t)wid * 64 + k * 8 + lg] = vc;
    }
  } else {
    int pb2 = bid - 4096;
    proj_body(pb2 & 3, pb2 >> 2, t, x, Wt0, pb0, aw0, ab0,
              Pt, s1o, s2po, s2no, As, Bs);
  }
}

// ---------------------------------------------------------------------------
// Standalone proj (layer 1).
__global__ __launch_bounds__(256) void proj_kernel(
    const float* __restrict__ x, const unsigned short* __restrict__ Wt,
    const float* __restrict__ pb, const float* __restrict__ aw,
    const float* __restrict__ abp,
    unsigned short* __restrict__ Pt, float* __restrict__ s1o,
    unsigned short* __restrict__ s2po, unsigned short* __restrict__ s2no)
{
  __shared__ unsigned short As[64][40];
  __shared__ unsigned short Bs[64][40];
  proj_body(blockIdx.x, blockIdx.y, threadIdx.x, x, Wt, pb, aw, abp,
            Pt, s1o, s2po, s2no, As, Bs);
}

// ---------------------------------------------------------------------------
// Attention, LDS-staged f16 Pt, packed-f16 weight math. Mask = (pka|pks) or
// pks-only (selected by pointing pka at pks — OR is idempotent).
__global__ __launch_bounds__(512) void attn_kernel(
    const unsigned short* __restrict__ Pt,    // (B,H,DK,S) f16
    const float* __restrict__ s1a,            // (B,H,S), log2e-scaled
    const unsigned short* __restrict__ s2pa,  // f16 exp2(s2L)
    const unsigned short* __restrict__ s2na,  // f16 exp2(0.2*s2L)
    const unsigned int* __restrict__ pka,     // adj==0 bits
    const unsigned int* __restrict__ pks,     // smask bits
    const int* __restrict__ typep,
    int layer,
    unsigned short* __restrict__ co)          // (B,S,M) f16 concat out
{
  __shared__ __align__(16) unsigned short ptl[32 * 512];  // 32KB, swizzled
  __shared__ __align__(16) unsigned short e2pl[1024];     // 2KB f16
  __shared__ __align__(16) unsigned short e2nl[1024];     // 2KB f16
  __shared__ uint4 mtab[256];                             // 4KB

  int orig = blockIdx.x;
  int lb = (orig & 7) * 64 + (orig >> 3);
  int iq = lb & 3, bh = lb >> 2;
  int b = bh >> 3, h = bh & 7;

  int t = threadIdx.x, w = t >> 6, lane = t & 63;
  int il = lane & 15, g4 = lane >> 4;
  int xorv = (il & 7) << 4;

  if (t < 256) {
    unsigned int m = t;
    uint4 e;
    e.x = ((m & 1u)   ? 0u : 0xFFFFu) | ((m & 2u)   ? 0u : 0xFFFF0000u);
    e.y = ((m & 4u)   ? 0u : 0xFFFFu) | ((m & 8u)   ? 0u : 0xFFFF0000u);
    e.z = ((m & 16u)  ? 0u : 0xFFFFu) | ((m & 32u)  ? 0u : 0xFFFF0000u);
    e.w = ((m & 64u)  ? 0u : 0xFFFFu) | ((m & 128u) ? 0u : 0xFFFF0000u);
    mtab[t] = e;
  }

  bool comb = !(typep[0] == 1 && layer > 0);
  const unsigned char* pa = (const unsigned char*)(comb ? pka : pks);
  const unsigned char* ps = (const unsigned char*)pks;
  const unsigned short* ptg = Pt + (size_t)bh * NDK * NS;

  f16x8 ones;
#pragma unroll
  for (int e = 0; e < 8; ++e) ones[e] = (_Float16)1.0f;

  int rbase = iq * 256 + w * 32;
  f16x2 e1p2[2], e1n2[2];
  size_t mbyte[2];
#pragma unroll
  for (int g = 0; g < 2; ++g) {
    float s1L = s1a[(size_t)bh * NS + rbase + g * 16 + il];
    s1L = fminf(fmaxf(s1L, -7.5f), 7.5f);
    _Float16 hp = (_Float16)EXP2F(s1L);
    _Float16 hn = (_Float16)EXP2F(0.2f * s1L);
    e1p2[g][0] = hp; e1p2[g][1] = hp;
    e1n2[g][0] = hn; e1n2[g][1] = hn;
    mbyte[g] = ((size_t)(b * NS + rbase + g * 16 + il) * NS) >> 3;
  }

  f32x4 acc[2][2] = {};
  f32x4 accd[2] = {};

  for (int jh = 0; jh < 2; ++jh) {
    __syncthreads();
    {
      const char* srcb = (const char*)ptg;
#pragma unroll
      for (int q = 0; q < 4; ++q) {
        int pos = q * 8192 + t * 16;
        int r = pos >> 10;
        int incol = pos & 1023;
        uint4 v = *(const uint4*)(srcb + r * 2048 + jh * 1024 + incol);
        *(uint4*)((char*)ptl + r * 1024 + (incol ^ ((r & 7) << 4))) = v;
      }
      if (jh == 0) {
        if (t < 128)
          ((uint4*)e2pl)[t] = *(const uint4*)(s2pa + (size_t)bh * NS + t * 8);
        else if (t < 256)
          ((uint4*)e2nl)[t - 128] =
              *(const uint4*)(s2na + (size_t)bh * NS + (t - 128) * 8);
      }
    }
    __syncthreads();

    for (int jg = 0; jg < 512; jg += 128) {
      size_t off = (size_t)((jh * 512 + jg) >> 3);
      uint4 ka0 = *(const uint4*)(pa + mbyte[0] + off);
      uint4 ks0 = *(const uint4*)(ps + mbyte[0] + off);
      uint4 ka1 = *(const uint4*)(pa + mbyte[1] + off);
      uint4 ks1 = *(const uint4*)(ps + mbyte[1] + off);
      uint4 mk0, mk1;
      mk0.x = ka0.x | ks0.x; mk0.y = ka0.y | ks0.y;
      mk0.z = ka0.z | ks0.z; mk0.w = ka0.w | ks0.w;
      mk1.x = ka1.x | ks1.x; mk1.y = ka1.y | ks1.y;
      mk1.z = ka1.z | ks1.z; mk1.w = ka1.w | ks1.w;
#pragma unroll
      for (int s = 0; s < 4; ++s) {
        unsigned int mb0 = ((&mk0.x)[s] >> (g4 * 8)) & 0xFFu;
        unsigned int mb1 = ((&mk1.x)[s] >> (g4 * 8)) & 0xFFu;
        uint4 am0 = mtab[mb0];
        uint4 am1 = mtab[mb1];
        int jl = jg + s * 32 + g4 * 8;
        int coff = (jl * 2) ^ xorv;
        const char* prow = (const char*)ptl + il * 1024;
        f16x8 b0 = *(const f16x8*)(prow + coff);
        f16x8 b1 = *(const f16x8*)(prow + 16 * 1024 + coff);
        int jfull = jh * 512 + jl;
        uint4 p4 = *(const uint4*)&e2pl[jfull];
        uint4 n4 = *(const uint4*)&e2nl[jfull];
        uint4 w0, w1;
        w0.x = wword(p4.x, n4.x, e1p2[0], e1n2[0], am0.x);
        w0.y = wword(p4.y, n4.y, e1p2[0], e1n2[0], am0.y);
        w0.z = wword(p4.z, n4.z, e1p2[0], e1n2[0], am0.z);
        w0.w = wword(p4.w, n4.w, e1p2[0], e1n2[0], am0.w);
        w1.x = wword(p4.x, n4.x, e1p2[1], e1n2[1], am1.x);
        w1.y = wword(p4.y, n4.y, e1p2[1], e1n2[1], am1.y);
        w1.z = wword(p4.z, n4.z, e1p2[1], e1n2[1], am1.z);
        w1.w = wword(p4.w, n4.w, e1p2[1], e1n2[1], am1.w);
        f16x8 af0 = __builtin_bit_cast(f16x8, w0);
        f16x8 af1 = __builtin_bit_cast(f16x8, w1);
        acc[0][0] = __builtin_amdgcn_mfma_f32_16x16x32_f16(af0, b0, acc[0][0], 0, 0, 0);
        acc[0][1] = __builtin_amdgcn_mfma_f32_16x16x32_f16(af0, b1, acc[0][1], 0, 0, 0);
        accd[0]   = __builtin_amdgcn_mfma_f32_16x16x32_f16(af0, ones, accd[0], 0, 0, 0);
        acc[1][0] = __builtin_amdgcn_mfma_f32_16x16x32_f16(af1, b0, acc[1][0], 0, 0, 0);
        acc[1][1] = __builtin_amdgcn_mfma_f32_16x16x32_f16(af1, b1, acc[1][1], 0, 0, 0);
        accd[1]   = __builtin_amdgcn_mfma_f32_16x16x32_f16(af1, ones, accd[1], 0, 0, 0);
      }
    }
  }

#pragma unroll
  for (int g = 0; g < 2; ++g) {
    f32x4 rd;
#pragma unroll
    for (int e = 0; e < 4; ++e) rd[e] = __builtin_amdgcn_rcpf(accd[g][e]);
    unsigned short* cob =
        co + (size_t)(b * NS + rbase + g * 16 + g4 * 4) * NM + h * 32 + il;
#pragma unroll
    for (int e = 0; e < 4; ++e) {
      cob[(size_t)e * NM] = f2h(acc[g][0][e] * rd[e]);
      cob[(size_t)e * NM + 16] = f2h(acc[g][1][e] * rd[e]);
    }
  }
}

// ---------------------------------------------------------------------------
// Residual + LayerNorm: row r -> LN(xin[r] + co[r]) * g + b.  co is f16.
__global__ __launch_bounds__(256) void ln_kernel(
    const float* __restrict__ xin, const unsigned short* __restrict__ co,
    const float* __restrict__ lng, const float* __restrict__ lnb,
    float* __restrict__ xout)
{
  int row = blockIdx.x * 4 + (threadIdx.x >> 6);
  int lane = threadIdx.x & 63;
  size_t base = (size_t)row * NM + lane * 4;
  ushort4 cv = *(const ushort4*)(co + base);
  f32x4 xv = *(const f32x4*)(xin + base);
  f32x4 r;
  r[0] = xv[0] + h2f(cv.x);
  r[1] = xv[1] + h2f(cv.y);
  r[2] = xv[2] + h2f(cv.z);
  r[3] = xv[3] + h2f(cv.w);
  float sm = r[0] + r[1] + r[2] + r[3];
  float sq = r[0] * r[0] + r[1] * r[1] + r[2] * r[2] + r[3] * r[3];
#pragma unroll
  for (int off = 32; off >= 1; off >>= 1) {
    sm += __shfl_xor(sm, off, 64);
    sq += __shfl_xor(sq, off, 64);
  }
  float mu = sm * (1.f / 256.f);
  float var = sq * (1.f / 256.f) - mu * mu;
  float inv = rsqrtf(var + 1e-5f);
  f32x4 gv = *(const f32x4*)(lng + lane * 4);
  f32x4 bv = *(const f32x4*)(lnb + lane * 4);
  f32x4 o;
#pragma unroll
  for (int e = 0; e < 4; ++e) o[e] = (r[e] - mu) * inv * gv[e] + bv[e];
  *(f32x4*)(xout + base) = o;
}

// ---------------------------------------------------------------------------
extern "C" void kernel_launch(void* const* d_in, const int* in_sizes, int n_in,
                              void* d_out, int out_size, void* d_ws, size_t ws_size,
                              hipStream_t stream)
{
  const int* adj = (const int*)d_in[0];
  const float* inputs = (const float*)d_in[1];
  const int* smask = (const int*)d_in[2];
  const int* typep = (const int*)d_in[3];
  const float* proj_w = (const float*)d_in[4];
  const float* proj_b = (const float*)d_in[5];
  const float* attn_w = (const float*)d_in[6];
  const float* attn_b = (const float*)d_in[7];
  const float* ln_g = (const float*)d_in[8];
  const float* ln_b = (const float*)d_in[9];
  float* out = (float*)d_out;

  char* ws = (char*)d_ws;
  unsigned int* pka = (unsigned int*)(ws);                      // 2 MB
  unsigned int* pks = (unsigned int*)(ws + (2u << 20));         // 2 MB
  unsigned short* Pt = (unsigned short*)(ws + (4u << 20));      // 8 MB
  float* s1 = (float*)(ws + (12u << 20));                       // 512 KB
  unsigned short* s2p = (unsigned short*)(ws + (12u << 20) + (1u << 19)); // 256 KB
  unsigned short* s2n = (unsigned short*)(ws + (13u << 20));    // 256 KB
  float* x1 = (float*)(ws + (14u << 20));                       // 16 MB
  unsigned short* Wt = (unsigned short*)(ws + (30u << 20));     // 256 KB
  unsigned short* co = (unsigned short*)(ws + (31u << 20));     // 8 MB f16

  wprep_kernel<<<16, 256, 0, stream>>>(proj_w, Wt);
  // Layer 0: mask packing overlapped with projection in one grid.
  prelude_kernel<<<5120, 256, 0, stream>>>(
      adj, smask, pka, pks, inputs, Wt, proj_b, attn_w, attn_b,
      Pt, s1, s2p, s2n);
  attn_kernel<<<512, 512, 0, stream>>>(
      Pt, s1, s2p, s2n, pka, pks, typep, 0, co);
  ln_kernel<<<4096, 256, 0, stream>>>(inputs, co, ln_g, ln_b, x1);
  // Layer 1.
  proj_kernel<<<dim3(4, 256), 256, 0, stream>>>(
      x1, Wt + (size_t)NH * NDK * NM, proj_b + (size_t)NH * NDK,
      attn_w + 64, attn_b + 1, Pt, s1, s2p, s2n);
  attn_kernel<<<512, 512, 0, stream>>>(
      Pt, s1, s2p, s2n, pka, pks, typep, 1, co);
  ln_kernel<<<4096, 256, 0, stream>>>(x1, co, ln_g + NM, ln_b + NM, out);
}